// Round 12
// baseline (143.270 us; speedup 1.0000x reference)
//
#include <hip/hip_runtime.h>

// GridEncoder (instant-NGP hash grid) forward, D=3, L=16, C=2, base_res=16,
// per_level_scale=2.0, log2_hashmap=19, align_corners=False.
//
// NUMERICS (verified R3-R10, absmax 4.8e-7): reference is JAX/XLA; jnp.exp2
// lowers to exp(x*ln2_f32) so scales are exact 16*2^l-1 EXCEPT
//   l=13 -> 131071.0625, l=15 -> 524286.75.
// pos = mul-round then add-round (no FMA); weights ((wx*wy)*wz) and the
// k=0..7 accumulation order kept op-by-op in f32 (__fmul_rn/__fadd_rn).
//
// Perf model (R5-R10): per-XCD L2 request count sets makespan; measured
// 24.7 G req/s/XCD with ~ideal weighted balance (R10, 120us total).
// R11 experiment: 2 points/thread (independent A/B streams, loads issued
// back-to-back per k2) to double per-wave loads-in-flight. Discriminates
// (i) L2 tag-rate bound (null) vs (ii) MSHR*latency bound (-10..20%).

constexpr int NLEV  = 16;
constexpr int BLK   = 256;
constexpr int CHUNK = 512;   // 2 points per thread

struct Bounds { int s[9]; };   // chunk-sequence boundaries per XCD

template<bool TO_WS, bool BALANCED>
__global__ __launch_bounds__(BLK) void grid_gather(
    const float* __restrict__ inputs,
    const float2* __restrict__ emb,
    const int* __restrict__ offsets,
    float2* __restrict__ dst,     // TO_WS: ws layout [l][b]; else out layout [b][l]
    int B, int chunks, Bounds bounds)
{
    // XLA-faithful scales (see header)
    const float SCALES[NLEV] = {
        15.f, 31.f, 63.f, 127.f, 255.f, 511.f, 1023.f, 2047.f,
        4095.f, 8191.f, 16383.f, 32767.f, 65535.f,
        131071.0625f,            // l=13 (XLA exp2 quirk)
        262143.f,
        524286.75f               // l=15 (XLA exp2 quirk)
    };

    int l, chunk;
    if (BALANCED) {
        // XCD = blockIdx%8 (round-robin dispatch; R6 verified via FETCH drop).
        int xcd = blockIdx.x & 7;
        int j   = blockIdx.x >> 3;
        int c   = bounds.s[xcd] + j;
        if (c >= bounds.s[xcd + 1]) return;   // padding block
        l = c / chunks;
        chunk = c - l * chunks;
    } else {
        l = blockIdx.x / chunks;
        chunk = blockIdx.x - l * chunks;
    }
    int bA = chunk * CHUNK + threadIdx.x;
    if (bA >= B) return;
    int  bB  = bA + BLK;
    bool vB  = bB < B;
    int  bBc = vB ? bB : bA;      // clamp: stream B duplicates A on tail (store masked)

    float xA = inputs[(size_t)bA * 3 + 0];
    float yA = inputs[(size_t)bA * 3 + 1];
    float zA = inputs[(size_t)bA * 3 + 2];
    float xB = inputs[(size_t)bBc * 3 + 0];
    float yB = inputs[(size_t)bBc * 3 + 1];
    float zB = inputs[(size_t)bBc * 3 + 2];

    int off0  = offsets[l];
    int hsize = offsets[l + 1] - off0;
    int res   = 16 << l;
    float scale = SCALES[l];
    long long r3 = (long long)res * res * res;
    bool use_hash = r3 > (long long)hsize;  // block-uniform (levels 3..15)
    uint32_t uh   = (uint32_t)hsize;
    bool     pow2 = (uh & (uh - 1u)) == 0u;

    // pos: mul-round then add-round, exactly as XLA's two elementwise ops
    float pxA = __fadd_rn(__fmul_rn(xA, scale), 0.5f);
    float pyA = __fadd_rn(__fmul_rn(yA, scale), 0.5f);
    float pzA = __fadd_rn(__fmul_rn(zA, scale), 0.5f);
    float pxB = __fadd_rn(__fmul_rn(xB, scale), 0.5f);
    float pyB = __fadd_rn(__fmul_rn(yB, scale), 0.5f);
    float pzB = __fadd_rn(__fmul_rn(zB, scale), 0.5f);
    float gxA = floorf(pxA), gyA = floorf(pyA), gzA = floorf(pzA);
    float gxB = floorf(pxB), gyB = floorf(pyB), gzB = floorf(pzB);
    float fxA = __fsub_rn(pxA, gxA), fyA = __fsub_rn(pyA, gyA), fzA = __fsub_rn(pzA, gzA);
    float fxB = __fsub_rn(pxB, gxB), fyB = __fsub_rn(pyB, gyB), fzB = __fsub_rn(pzB, gzB);
    int pgxA = (int)gxA, pgyA = (int)gyA, pgzA = (int)gzA;
    int pgxB = (int)gxB, pgyB = (int)gyB, pgzB = (int)gzB;
    float omxA = __fsub_rn(1.0f, fxA), omyA = __fsub_rn(1.0f, fyA), omzA = __fsub_rn(1.0f, fzA);
    float omxB = __fsub_rn(1.0f, fxB), omyB = __fsub_rn(1.0f, fyB), omzB = __fsub_rn(1.0f, fzB);

    float r0A = 0.0f, r1A = 0.0f, r0B = 0.0f, r1B = 0.0f;
    const float2* tab = emb + (size_t)off0;   // 64B-aligned (off0 % 8 == 0)

    if (use_hash && pow2) {
        const uint32_t mask = uh - 1u;
        #pragma unroll
        for (int k2 = 0; k2 < 4; ++k2) {
            const int by = k2 & 1, bz = (k2 >> 1) & 1;
            uint32_t mA = ((uint32_t)(pgyA + by) * 2654435761u)
                        ^ ((uint32_t)(pgzA + bz) * 805459861u);
            uint32_t mB = ((uint32_t)(pgyB + by) * 2654435761u)
                        ^ ((uint32_t)(pgzB + bz) * 805459861u);
            uint32_t i0A = ((uint32_t)pgxA ^ mA) & mask;
            uint32_t i1A = ((uint32_t)(pgxA + 1) ^ mA) & mask;
            uint32_t i0B = ((uint32_t)pgxB ^ mB) & mask;
            uint32_t i1B = ((uint32_t)(pgxB + 1) ^ mB) & mask;
            // 4 independent pair-line loads back-to-back (MLP)
            float4 qA0 = *(const float4*)(tab + (i0A & ~1u));
            float4 qA1 = *(const float4*)(tab + (i1A & ~1u));
            float4 qB0 = *(const float4*)(tab + (i0B & ~1u));
            float4 qB1 = *(const float4*)(tab + (i1B & ~1u));
            float2 vA0 = (i0A & 1u) ? make_float2(qA0.z, qA0.w) : make_float2(qA0.x, qA0.y);
            float2 vA1 = (i1A & 1u) ? make_float2(qA1.z, qA1.w) : make_float2(qA1.x, qA1.y);
            float2 vB0 = (i0B & 1u) ? make_float2(qB0.z, qB0.w) : make_float2(qB0.x, qB0.y);
            float2 vB1 = (i1B & 1u) ? make_float2(qB1.z, qB1.w) : make_float2(qB1.x, qB1.y);
            float wyA = by ? fyA : omyA, wzA = bz ? fzA : omzA;
            float wyB = by ? fyB : omyB, wzB = bz ? fzB : omzB;
            float w0A = __fmul_rn(__fmul_rn(omxA, wyA), wzA);  // ((wx*wy)*wz)
            float w1A = __fmul_rn(__fmul_rn(fxA,  wyA), wzA);
            float w0B = __fmul_rn(__fmul_rn(omxB, wyB), wzB);
            float w1B = __fmul_rn(__fmul_rn(fxB,  wyB), wzB);
            // per point: accumulation order == reference k = 2*k2, 2*k2+1
            r0A = __fadd_rn(r0A, __fmul_rn(w0A, vA0.x));
            r1A = __fadd_rn(r1A, __fmul_rn(w0A, vA0.y));
            r0A = __fadd_rn(r0A, __fmul_rn(w1A, vA1.x));
            r1A = __fadd_rn(r1A, __fmul_rn(w1A, vA1.y));
            r0B = __fadd_rn(r0B, __fmul_rn(w0B, vB0.x));
            r1B = __fadd_rn(r1B, __fmul_rn(w0B, vB0.y));
            r0B = __fadd_rn(r0B, __fmul_rn(w1B, vB1.x));
            r1B = __fadd_rn(r1B, __fmul_rn(w1B, vB1.y));
        }
    } else {
        // dense levels 0..2: corner bx=1 index = di0+1 (pre-mod), same
        // branch-free pair-line structure, two streams.
        #pragma unroll
        for (int k2 = 0; k2 < 4; ++k2) {
            const int by = k2 & 1, bz = (k2 >> 1) & 1;
            int diA = pgxA + (pgyA + by) * res + (pgzA + bz) * res * res;
            int diB = pgxB + (pgyB + by) * res + (pgzB + bz) * res * res;
            uint32_t i0A = (uint32_t)(diA % hsize);
            uint32_t i1A = (uint32_t)((diA + 1) % hsize);
            uint32_t i0B = (uint32_t)(diB % hsize);
            uint32_t i1B = (uint32_t)((diB + 1) % hsize);
            float4 qA0 = *(const float4*)(tab + (i0A & ~1u));
            float4 qA1 = *(const float4*)(tab + (i1A & ~1u));
            float4 qB0 = *(const float4*)(tab + (i0B & ~1u));
            float4 qB1 = *(const float4*)(tab + (i1B & ~1u));
            float2 vA0 = (i0A & 1u) ? make_float2(qA0.z, qA0.w) : make_float2(qA0.x, qA0.y);
            float2 vA1 = (i1A & 1u) ? make_float2(qA1.z, qA1.w) : make_float2(qA1.x, qA1.y);
            float2 vB0 = (i0B & 1u) ? make_float2(qB0.z, qB0.w) : make_float2(qB0.x, qB0.y);
            float2 vB1 = (i1B & 1u) ? make_float2(qB1.z, qB1.w) : make_float2(qB1.x, qB1.y);
            float wyA = by ? fyA : omyA, wzA = bz ? fzA : omzA;
            float wyB = by ? fyB : omyB, wzB = bz ? fzB : omzB;
            float w0A = __fmul_rn(__fmul_rn(omxA, wyA), wzA);
            float w1A = __fmul_rn(__fmul_rn(fxA,  wyA), wzA);
            float w0B = __fmul_rn(__fmul_rn(omxB, wyB), wzB);
            float w1B = __fmul_rn(__fmul_rn(fxB,  wyB), wzB);
            r0A = __fadd_rn(r0A, __fmul_rn(w0A, vA0.x));
            r1A = __fadd_rn(r1A, __fmul_rn(w0A, vA0.y));
            r0A = __fadd_rn(r0A, __fmul_rn(w1A, vA1.x));
            r1A = __fadd_rn(r1A, __fmul_rn(w1A, vA1.y));
            r0B = __fadd_rn(r0B, __fmul_rn(w0B, vB0.x));
            r1B = __fadd_rn(r1B, __fmul_rn(w0B, vB0.y));
            r0B = __fadd_rn(r0B, __fmul_rn(w1B, vB1.x));
            r1B = __fadd_rn(r1B, __fmul_rn(w1B, vB1.y));
        }
    }

    if (TO_WS) {
        dst[(size_t)l * B + bA] = make_float2(r0A, r1A);           // coalesced
        if (vB) dst[(size_t)l * B + bB] = make_float2(r0B, r1B);
    } else {
        dst[(size_t)bA * NLEV + l] = make_float2(r0A, r1A);        // strided fallback
        if (vB) dst[(size_t)bB * NLEV + l] = make_float2(r0B, r1B);
    }
}

// ws [l][b] (float2, l-major) -> out [b][l*2+c]; LDS-staged, 64 points/block,
// 8KB contiguous global write per block.
__global__ __launch_bounds__(256) void transpose_lds(
    const float4* __restrict__ ws4,   // ws viewed as float4: [NLEV][B/2]
    float4* __restrict__ out4,        // out viewed as float4: [B][8]
    int B)
{
    __shared__ float2 lds[64][17];    // +1 pad breaks pow2 bank stride
    int halfB = B >> 1;               // B even
    int b0 = blockIdx.x * 64;         // 64 points per block
    int t = threadIdx.x;

    #pragma unroll
    for (int rep = 0; rep < 2; ++rep) {
        int idx = t + rep * 256;
        int l = idx >> 5, p = idx & 31;
        int gp = (b0 >> 1) + p;
        if (gp < halfB) {
            float4 q = ws4[(size_t)l * halfB + gp];   // 512B contiguous per level
            lds[2 * p][l]     = make_float2(q.x, q.y);
            lds[2 * p + 1][l] = make_float2(q.z, q.w);
        }
    }
    __syncthreads();

    #pragma unroll
    for (int rep = 0; rep < 2; ++rep) {
        int idx = t + rep * 256;
        int pt = idx >> 3, c = idx & 7;
        int gb = b0 + pt;
        if (gb < B) {
            float2 a  = lds[pt][2 * c];
            float2 b2 = lds[pt][2 * c + 1];
            out4[(size_t)gb * 8 + c] = make_float4(a.x, a.y, b2.x, b2.y);
        }
    }
}

// fallback (odd B): 1 point/thread, per-lane-contiguous writes
__global__ __launch_bounds__(256) void transpose_out1(
    const float2* __restrict__ ws,
    float2* __restrict__ out,
    int B)
{
    int b = blockIdx.x * 256 + threadIdx.x;
    if (b >= B) return;
    float2 v[NLEV];
    #pragma unroll
    for (int l = 0; l < NLEV; ++l)
        v[l] = ws[(size_t)l * B + b];
    float4* o = (float4*)(out + (size_t)b * NLEV);
    #pragma unroll
    for (int i = 0; i < 8; ++i)
        o[i] = make_float4(v[2*i].x, v[2*i].y, v[2*i+1].x, v[2*i+1].y);
}

// host-side weighted partition of the level-major chunk sequence.
// weights (x10): l0=1 (L1-resident), l1=8, l2..l15=10.
static int sched_boundary_host(int x, int K) {
    const int Wt[16] = {1,8,10,10,10,10,10,10,10,10,10,10,10,10,10,10};
    long long WT = 0;
    for (int l = 0; l < 16; ++l) WT += (long long)K * Wt[l];
    long long target = (long long)x * WT;
    long long pref = 0;
    for (int l = 0; l < 16; ++l) {
        long long lvlW = (long long)K * Wt[l];
        if (8 * (pref + lvlW) >= target) {
            long long need = target - 8 * pref;
            long long t = need <= 0 ? 0 : (need + 8LL * Wt[l] - 1) / (8LL * Wt[l]);
            return (int)((long long)l * K + t);
        }
        pref += lvlW;
    }
    return 16 * K;
}

extern "C" void kernel_launch(void* const* d_in, const int* in_sizes, int n_in,
                              void* d_out, int out_size, void* d_ws, size_t ws_size,
                              hipStream_t stream) {
    const float*  inputs  = (const float*)d_in[0];
    const float2* emb     = (const float2*)d_in[1];
    const int*    offsets = (const int*)d_in[2];
    float2*       out     = (float2*)d_out;
    int B = in_sizes[0] / 3;
    int chunks = (B + CHUNK - 1) / CHUNK;

    Bounds bounds;
    int maxC = 0;
    for (int x = 0; x <= 8; ++x) bounds.s[x] = sched_boundary_host(x, chunks);
    for (int x = 0; x < 8; ++x) {
        int c = bounds.s[x + 1] - bounds.s[x];
        if (c > maxC) maxC = c;
    }

    bool use_ws = ws_size >= (size_t)B * NLEV * sizeof(float2);
    if (use_ws) {
        int grid = 8 * maxC;   // padding blocks exit instantly
        float2* ws = (float2*)d_ws;
        hipLaunchKernelGGL((grid_gather<true, true>), dim3(grid), dim3(BLK), 0, stream,
                           inputs, emb, offsets, ws, B, chunks, bounds);
        if ((B & 1) == 0) {
            hipLaunchKernelGGL(transpose_lds, dim3((B + 63) / 64), dim3(256), 0, stream,
                               (const float4*)ws, (float4*)out, B);
        } else {
            hipLaunchKernelGGL(transpose_out1, dim3((B + 255) / 256), dim3(256), 0, stream,
                               ws, out, B);
        }
    } else {
        hipLaunchKernelGGL((grid_gather<false, false>), dim3(NLEV * chunks), dim3(BLK), 0, stream,
                           inputs, emb, offsets, out, B, chunks, bounds);
    }
}

// Round 13
// 119.889 us; speedup vs baseline: 1.1950x; 1.1950x over previous
//
#include <hip/hip_runtime.h>

// GridEncoder (instant-NGP hash grid) forward, D=3, L=16, C=2, base_res=16,
// per_level_scale=2.0, log2_hashmap=19, align_corners=False.
//
// NUMERICS (verified R3-R12, absmax 4.8e-7): reference is JAX/XLA; jnp.exp2
// lowers to exp(x*ln2_f32) so scales are exact 16*2^l-1 EXCEPT
//   l=13 -> 131071.0625, l=15 -> 524286.75.
// pos = mul-round then add-round (no FMA); weights ((wx*wy)*wz) and the
// k=0..7 accumulation order kept op-by-op in f32 (__fmul_rn/__fadd_rn).
//
// FINAL perf model (R4-R11 evidence): per-XCD L2 request rate is the
// binding resource (~24.7 G req/s/XCD). Critical XCD = 1.86 level-equivs
// x 250k pts x 6 lane-requests = 2.79M req => ~113us gather floor; +7us
// transpose. This kernel (== R10) measures 120us total.
// Levers tested and rejected: R7 load-hoist (regressed, compiler owns the
// schedule), R9 exec-masked dup-skip (dup line is an L1 hit; branch cost
// only), R11 2-pts/thread MLP (occupancy halves, regressed). Levers kept:
// level-major two-pass (R4), pair-line float4 gathers via prime[0]==1 (R5),
// XCD-pinned levels via blockIdx%8 (R6), host-side weighted rebalance (R10),
// LDS transpose with 8KB-contiguous block writes (R6/R7).

constexpr int NLEV = 16;
constexpr int BLK  = 256;

struct Bounds { int s[9]; };   // chunk-sequence boundaries per XCD

template<bool TO_WS, bool BALANCED>
__global__ __launch_bounds__(BLK) void grid_gather(
    const float* __restrict__ inputs,
    const float2* __restrict__ emb,
    const int* __restrict__ offsets,
    float2* __restrict__ dst,     // TO_WS: ws layout [l][b]; else out layout [b][l]
    int B, int chunks, Bounds bounds)
{
    // XLA-faithful scales (see header)
    const float SCALES[NLEV] = {
        15.f, 31.f, 63.f, 127.f, 255.f, 511.f, 1023.f, 2047.f,
        4095.f, 8191.f, 16383.f, 32767.f, 65535.f,
        131071.0625f,            // l=13 (XLA exp2 quirk)
        262143.f,
        524286.75f               // l=15 (XLA exp2 quirk)
    };

    int l, chunk;
    if (BALANCED) {
        // XCD = blockIdx%8 (round-robin dispatch; R6 verified via FETCH drop).
        int xcd = blockIdx.x & 7;
        int j   = blockIdx.x >> 3;
        int c   = bounds.s[xcd] + j;
        if (c >= bounds.s[xcd + 1]) return;   // padding block
        l = c / chunks;
        chunk = c - l * chunks;
    } else {
        l = blockIdx.x / chunks;
        chunk = blockIdx.x - l * chunks;
    }
    int b = chunk * BLK + threadIdx.x;
    if (b >= B) return;

    float x = inputs[(size_t)b * 3 + 0];
    float y = inputs[(size_t)b * 3 + 1];
    float z = inputs[(size_t)b * 3 + 2];

    int off0  = offsets[l];
    int hsize = offsets[l + 1] - off0;
    int res   = 16 << l;
    float scale = SCALES[l];
    long long r3 = (long long)res * res * res;
    bool use_hash = r3 > (long long)hsize;  // block-uniform (levels 3..15)
    uint32_t uh   = (uint32_t)hsize;
    bool     pow2 = (uh & (uh - 1u)) == 0u;

    // pos: mul-round then add-round, exactly as XLA's two elementwise ops
    float px = __fadd_rn(__fmul_rn(x, scale), 0.5f);
    float py = __fadd_rn(__fmul_rn(y, scale), 0.5f);
    float pz = __fadd_rn(__fmul_rn(z, scale), 0.5f);
    float gx = floorf(px), gy = floorf(py), gz = floorf(pz);
    float fx = __fsub_rn(px, gx), fy = __fsub_rn(py, gy), fz = __fsub_rn(pz, gz);
    int pgx = (int)gx, pgy = (int)gy, pgz = (int)gz;
    float omx = __fsub_rn(1.0f, fx), omy = __fsub_rn(1.0f, fy), omz = __fsub_rn(1.0f, fz);

    float r0 = 0.0f, r1 = 0.0f;
    const float2* tab = emb + (size_t)off0;   // 64B-aligned (off0 % 8 == 0)

    if (use_hash && pow2) {
        const uint32_t mask = uh - 1u;
        #pragma unroll
        for (int k2 = 0; k2 < 4; ++k2) {
            const int by = k2 & 1, bz = (k2 >> 1) & 1;
            uint32_t m = ((uint32_t)(pgy + by) * 2654435761u)
                       ^ ((uint32_t)(pgz + bz) * 805459861u);
            uint32_t i0 = ((uint32_t)pgx ^ m) & mask;        // corner bx=0
            uint32_t i1 = ((uint32_t)(pgx + 1) ^ m) & mask;  // corner bx=1
            // pair-line loads, 16B aligned; even-pgx lanes: 2nd is an L1 hit
            float4 q0 = *(const float4*)(tab + (i0 & ~1u));
            float4 q1 = *(const float4*)(tab + (i1 & ~1u));
            float2 v0 = (i0 & 1u) ? make_float2(q0.z, q0.w) : make_float2(q0.x, q0.y);
            float2 v1 = (i1 & 1u) ? make_float2(q1.z, q1.w) : make_float2(q1.x, q1.y);
            float wy = by ? fy : omy;
            float wz = bz ? fz : omz;
            float w0 = __fmul_rn(__fmul_rn(omx, wy), wz);  // ((wx*wy)*wz) order
            float w1 = __fmul_rn(__fmul_rn(fx,  wy), wz);
            // accumulation order == reference k = 2*k2, 2*k2+1
            r0 = __fadd_rn(r0, __fmul_rn(w0, v0.x));
            r1 = __fadd_rn(r1, __fmul_rn(w0, v0.y));
            r0 = __fadd_rn(r0, __fmul_rn(w1, v1.x));
            r1 = __fadd_rn(r1, __fmul_rn(w1, v1.y));
        }
    } else {
        // dense levels 0..2: corner bx=1 index = di0+1 (pre-mod), same
        // branch-free pair-line structure.
        #pragma unroll
        for (int k2 = 0; k2 < 4; ++k2) {
            const int by = k2 & 1, bz = (k2 >> 1) & 1;
            int di0 = pgx + (pgy + by) * res + (pgz + bz) * res * res;
            uint32_t i0 = (uint32_t)(di0 % hsize);          // mirrors reference %
            uint32_t i1 = (uint32_t)((di0 + 1) % hsize);
            float4 q0 = *(const float4*)(tab + (i0 & ~1u));
            float4 q1 = *(const float4*)(tab + (i1 & ~1u));
            float2 v0 = (i0 & 1u) ? make_float2(q0.z, q0.w) : make_float2(q0.x, q0.y);
            float2 v1 = (i1 & 1u) ? make_float2(q1.z, q1.w) : make_float2(q1.x, q1.y);
            float wy = by ? fy : omy;
            float wz = bz ? fz : omz;
            float w0 = __fmul_rn(__fmul_rn(omx, wy), wz);
            float w1 = __fmul_rn(__fmul_rn(fx,  wy), wz);
            r0 = __fadd_rn(r0, __fmul_rn(w0, v0.x));
            r1 = __fadd_rn(r1, __fmul_rn(w0, v0.y));
            r0 = __fadd_rn(r0, __fmul_rn(w1, v1.x));
            r1 = __fadd_rn(r1, __fmul_rn(w1, v1.y));
        }
    }

    if (TO_WS)
        dst[(size_t)l * B + b] = make_float2(r0, r1);      // coalesced
    else
        dst[(size_t)b * NLEV + l] = make_float2(r0, r1);   // strided fallback
}

// ws [l][b] (float2, l-major) -> out [b][l*2+c]; LDS-staged, 64 points/block,
// 8KB contiguous global write per block.
__global__ __launch_bounds__(256) void transpose_lds(
    const float4* __restrict__ ws4,   // ws viewed as float4: [NLEV][B/2]
    float4* __restrict__ out4,        // out viewed as float4: [B][8]
    int B)
{
    __shared__ float2 lds[64][17];    // +1 pad breaks pow2 bank stride
    int halfB = B >> 1;               // B even
    int b0 = blockIdx.x * 64;         // 64 points per block
    int t = threadIdx.x;

    #pragma unroll
    for (int rep = 0; rep < 2; ++rep) {
        int idx = t + rep * 256;
        int l = idx >> 5, p = idx & 31;
        int gp = (b0 >> 1) + p;
        if (gp < halfB) {
            float4 q = ws4[(size_t)l * halfB + gp];   // 512B contiguous per level
            lds[2 * p][l]     = make_float2(q.x, q.y);
            lds[2 * p + 1][l] = make_float2(q.z, q.w);
        }
    }
    __syncthreads();

    #pragma unroll
    for (int rep = 0; rep < 2; ++rep) {
        int idx = t + rep * 256;
        int pt = idx >> 3, c = idx & 7;
        int gb = b0 + pt;
        if (gb < B) {
            float2 a  = lds[pt][2 * c];
            float2 b2 = lds[pt][2 * c + 1];
            out4[(size_t)gb * 8 + c] = make_float4(a.x, a.y, b2.x, b2.y);
        }
    }
}

// fallback (odd B): 1 point/thread, per-lane-contiguous writes
__global__ __launch_bounds__(256) void transpose_out1(
    const float2* __restrict__ ws,
    float2* __restrict__ out,
    int B)
{
    int b = blockIdx.x * 256 + threadIdx.x;
    if (b >= B) return;
    float2 v[NLEV];
    #pragma unroll
    for (int l = 0; l < NLEV; ++l)
        v[l] = ws[(size_t)l * B + b];
    float4* o = (float4*)(out + (size_t)b * NLEV);
    #pragma unroll
    for (int i = 0; i < 8; ++i)
        o[i] = make_float4(v[2*i].x, v[2*i].y, v[2*i+1].x, v[2*i+1].y);
}

// host-side weighted partition of the level-major chunk sequence.
// weights (x10): l0=1 (L1-resident), l1=8, l2..l15=10.
static int sched_boundary_host(int x, int K) {
    const int Wt[16] = {1,8,10,10,10,10,10,10,10,10,10,10,10,10,10,10};
    long long WT = 0;
    for (int l = 0; l < 16; ++l) WT += (long long)K * Wt[l];
    long long target = (long long)x * WT;
    long long pref = 0;
    for (int l = 0; l < 16; ++l) {
        long long lvlW = (long long)K * Wt[l];
        if (8 * (pref + lvlW) >= target) {
            long long need = target - 8 * pref;
            long long t = need <= 0 ? 0 : (need + 8LL * Wt[l] - 1) / (8LL * Wt[l]);
            return (int)((long long)l * K + t);
        }
        pref += lvlW;
    }
    return 16 * K;
}

extern "C" void kernel_launch(void* const* d_in, const int* in_sizes, int n_in,
                              void* d_out, int out_size, void* d_ws, size_t ws_size,
                              hipStream_t stream) {
    const float*  inputs  = (const float*)d_in[0];
    const float2* emb     = (const float2*)d_in[1];
    const int*    offsets = (const int*)d_in[2];
    float2*       out     = (float2*)d_out;
    int B = in_sizes[0] / 3;
    int chunks = (B + BLK - 1) / BLK;

    Bounds bounds;
    int maxC = 0;
    for (int x = 0; x <= 8; ++x) bounds.s[x] = sched_boundary_host(x, chunks);
    for (int x = 0; x < 8; ++x) {
        int c = bounds.s[x + 1] - bounds.s[x];
        if (c > maxC) maxC = c;
    }

    bool use_ws = ws_size >= (size_t)B * NLEV * sizeof(float2);
    if (use_ws) {
        int grid = 8 * maxC;   // padding blocks exit instantly
        float2* ws = (float2*)d_ws;
        hipLaunchKernelGGL((grid_gather<true, true>), dim3(grid), dim3(BLK), 0, stream,
                           inputs, emb, offsets, ws, B, chunks, bounds);
        if ((B & 1) == 0) {
            hipLaunchKernelGGL(transpose_lds, dim3((B + 63) / 64), dim3(256), 0, stream,
                               (const float4*)ws, (float4*)out, B);
        } else {
            hipLaunchKernelGGL(transpose_out1, dim3((B + 255) / 256), dim3(256), 0, stream,
                               ws, out, B);
        }
    } else {
        hipLaunchKernelGGL((grid_gather<false, false>), dim3(NLEV * chunks), dim3(BLK), 0, stream,
                           inputs, emb, offsets, out, B, chunks, bounds);
    }
}